// Round 1
// 2155.994 us; speedup vs baseline: 1.0740x; 1.0740x over previous
//
#include <hip/hip_runtime.h>

// ---------------------------------------------------------------------------
// RNN_Layer: x[B,T,C] fp32 -> conv1x1(w_in) -> dense(kernel) -> LSTM(rec)
//            -> dense(w_out).  B=32 T=1024 C=512 D=256 U=256 O=256.
// R7: LSTM recurrent GEMV moved from VALU (dot2/readlane) to the MFMA pipe.
// Per batch-WG (512 thr, 8 waves, 2 waves/SIMD = 256-VGPR budget):
//   wave w owns gate-column strips {2w,2w+1, 16+2w,16+2w+1, 32+2w,32+2w+1}
//   resident as f16 MFMA B-frags in 192 VGPRs (asm-pinned), plus streamed
//   o-gate strips {48+2w,48+2w+1} staged once into LDS (128 KB) and re-read
//   per step as linear ds_read_b128 (conflict-free).
// h lives in A-row 0 (lanes lr==0), all other A rows zero -> D row 0 = z.
// Strips paired so quad-0 lanes end each half-step with ALL FOUR gates of one
// unit -> gates computed in-lane, no z scratch, ONE barrier/step (h dbuf).
// ---------------------------------------------------------------------------

#define DEV static __device__ __forceinline__

typedef __attribute__((ext_vector_type(8))) short short8;
typedef __attribute__((ext_vector_type(4))) float floatx4;
typedef _Float16 half8 __attribute__((ext_vector_type(8)));

static constexpr int Bsz = 32, T = 1024, C = 512, D = 256, U = 256, FU = 1024;
static constexpr int M = Bsz * T;   // 32768 rows for all GEMMs

DEV float bfu2f(unsigned int u) { union { unsigned int i; float f; } v; v.i = u; return v.f; }
DEV float bf2f(unsigned short u) { return bfu2f(((unsigned int)u) << 16); }
DEV unsigned short f2bf(float f) {
    union { float f; unsigned int i; } v; v.f = f;
    return (unsigned short)((v.i + 0x7fffu + ((v.i >> 16) & 1u)) >> 16);
}
DEV float sigmf(float x) { return 1.0f / (1.0f + __expf(-x)); }
DEV float tanhfast(float x) {
    const float a = __expf(-2.0f * fabsf(x));
    const float t = (1.0f - a) / (1.0f + a);
    return copysignf(t, x);
}
DEV half8 h8c(uint4 v) { return __builtin_bit_cast(half8, v); }

// fp32-or-bf16 element -> bf16 bit pattern (GEMM operand loads)
DEV short ld_bf(const float* p) { return (short)f2bf(*p); }
DEV short ld_bf(const unsigned short* p) { return (short)*p; }
DEV short8 ld_frag(const unsigned short* p) { return *(const short8*)p; }
DEV short8 ld_frag(const float* p) {
    short8 v;
#pragma unroll
    for (int j = 0; j < 8; j++) v[j] = (short)f2bf(p[j]);
    return v;
}
DEV float ldxz1(const float* p) { return *p; }
DEV float ldxz1(const unsigned short* p) { return bf2f(*p); }

// ---------------------------------------------------------------------------
// Fragment-direct MFMA GEMM:  C[M,N] = A[M,K] @ B[K,N] + bias[N]
// One wave/block; wave owns NS 16-col strips (B frags in VGPRs), MT row tiles.
// Layouts (m89/m120-verified): A[m=lane&15][k=quad*8+j];
//   B[k=quad*8+j][n=lane&15]; D[m=quad*4+r][n=lane&15]
// ---------------------------------------------------------------------------
template <int K, int N, int MT, int NS, bool OUTF32, typename AT, typename BT>
__global__ __launch_bounds__(64) void gemm_mfma(
    const AT* __restrict__ A,
    const BT* __restrict__ Bm,
    const float* __restrict__ bias,
    void* __restrict__ Cv)
{
    constexpr int KC = K / 32;
    const int lane = threadIdx.x;
    const int quad = lane >> 4, lr = lane & 15;
    constexpr int NSG = N / (16 * NS);
    const int sg = blockIdx.x % NSG;
    const int mb = blockIdx.x / NSG;
    const int n0 = sg * 16 * NS;

    short8 bf[NS][KC];
    float biasv[NS];
#pragma unroll
    for (int s = 0; s < NS; s++) {
        const int n = n0 + s * 16 + lr;
        biasv[s] = bias[n];
#pragma unroll
        for (int kc = 0; kc < KC; kc++) {
            short8 v;
#pragma unroll
            for (int j = 0; j < 8; j++) {
                const int k = kc * 32 + quad * 8 + j;
                v[j] = ld_bf(&Bm[(size_t)k * N + n]);
            }
            bf[s][kc] = v;
        }
    }

    for (int mt = 0; mt < MT; mt++) {
        const int m0 = (mb * MT + mt) * 16;
        const AT* Ap = A + (size_t)(m0 + lr) * K + quad * 8;
        floatx4 acc[NS];
#pragma unroll
        for (int s = 0; s < NS; s++) acc[s] = (floatx4){0.f, 0.f, 0.f, 0.f};
#pragma unroll
        for (int kc = 0; kc < KC; kc++) {
            short8 af = ld_frag(Ap + kc * 32);
#pragma unroll
            for (int s = 0; s < NS; s++)
                acc[s] = __builtin_amdgcn_mfma_f32_16x16x32_bf16(af, bf[s][kc], acc[s], 0, 0, 0);
        }
#pragma unroll
        for (int s = 0; s < NS; s++) {
            const int n = n0 + s * 16 + lr;
#pragma unroll
            for (int r = 0; r < 4; r++) {
                const int m = m0 + quad * 4 + r;
                const float val = acc[s][r] + biasv[s];
                if (OUTF32)
                    ((float*)Cv)[(size_t)m * N + n] = val;
                else
                    ((unsigned short*)Cv)[(size_t)m * N + n] = f2bf(val);
            }
        }
    }
}

// ---------------------------------------------------------------------------
// Pack rec_kernel fp32 [256][1024] -> f16 MFMA B-fragments.
// Pm[(strip*8 + kc)*64 + lane] = ushort8 with element j =
//   f16( rec[ kc*32 + (lane>>4)*8 + j ][ strip*16 + (lane&15) ] )
// i.e. exactly the 16x16x32 B layout B[k=quad*8+j][n=lr] per (strip,kc).
// ---------------------------------------------------------------------------
__global__ __launch_bounds__(256) void pack_rec_mfma(const float* __restrict__ rec,
                                                     uint4* __restrict__ Pm)
{
    const int idx = blockIdx.x * 256 + threadIdx.x;   // 0..32767
    const int lane = idx & 63;
    const int kc = (idx >> 6) & 7;
    const int strip = idx >> 9;
    const int q = lane >> 4, lr = lane & 15;
    const int col = strip * 16 + lr;
    const int k0 = kc * 32 + q * 8;
    union { unsigned short u[8]; uint4 v; } out;
#pragma unroll
    for (int j = 0; j < 8; j++) {
        const _Float16 h = (_Float16)rec[(size_t)(k0 + j) * FU + col];
        out.u[j] = __builtin_bit_cast(unsigned short, h);
    }
    Pm[idx] = out.v;
}

// ---------------------------------------------------------------------------
// MFMA LSTM. 1 WG (512 thr / 8 waves, 2 waves/SIMD) per batch.
// Per step: A-frag = h (f16, lanes lr==0 from LDS h dbuf, other A rows 0);
// two half-steps, each = 8 kc x 4 MFMA (3 resident strips + 1 LDS strip),
// then the owning unit's 4 gates computed directly in quad-0 lanes.
// ---------------------------------------------------------------------------
template <typename XZT>
__global__ __attribute__((amdgpu_flat_work_group_size(512, 512),
                          amdgpu_waves_per_eu(2, 2)))
void lstm_mfma(
    const XZT* __restrict__ xz,            // [B, T, 4U]
    const uint4* __restrict__ Pm,          // packed rec frags, 32768 x 16B
    unsigned short* __restrict__ hs)       // [B, T, U] bf16 out
{
    const int b = blockIdx.x;
    const int tid = threadIdx.x;
    const int w = tid >> 6;                // wave 0..7
    const int lane = tid & 63;
    const int q = lane >> 4, lr = lane & 15;

    __shared__ uint4 Wl[16 * 8 * 64];                  // strips 48..63: 128 KiB
    __shared__ __align__(16) unsigned short hbuf[2][U];

    // stage streamed (o-gate) strips into LDS, once
    for (int i = tid; i < 16 * 8 * 64; i += 512)
        Wl[i] = Pm[48 * 8 * 64 + i];
    if (tid < U) { hbuf[0][tid] = 0; hbuf[1][tid] = 0; }

    // resident strips {2w, 2w+1, 16+2w, 16+2w+1, 32+2w, 32+2w+1}: 192 VGPRs
    uint4 Wr[6][8];
#pragma unroll
    for (int s = 0; s < 6; s++) {
        const int strip = (s >> 1) * 16 + 2 * w + (s & 1);
#pragma unroll
        for (int kc = 0; kc < 8; kc++)
            Wr[s][kc] = Pm[(strip * 8 + kc) * 64 + lane];
    }
    // opaque pin: prevent remat/spill of the resident block (R4/R5 lesson)
#pragma unroll
    for (int s = 0; s < 6; s++)
#pragma unroll
        for (int kc = 0; kc < 8; kc++)
            asm volatile("" : "+v"(Wr[s][kc].x), "+v"(Wr[s][kc].y),
                             "+v"(Wr[s][kc].z), "+v"(Wr[s][kc].w));
    __syncthreads();

    const XZT* xzb = xz + (size_t)b * T * FU;
    unsigned short* hsb = hs + (size_t)b * T * U;
    const int u0 = 32 * w + lr;            // unit owned in half A (quad-0 lanes)

    float c0 = 0.f, c1 = 0.f;
    float xc[8], xn[8];
#pragma unroll
    for (int i = 0; i < 8; i++) { xc[i] = 0.f; xn[i] = 0.f; }
    if (q == 0) {
#pragma unroll
        for (int g2 = 0; g2 < 4; g2++) {
            xc[2 * g2]     = ldxz1(xzb + g2 * 256 + u0);
            xc[2 * g2 + 1] = ldxz1(xzb + g2 * 256 + u0 + 16);
        }
    }

    const uint4 z4 = {0u, 0u, 0u, 0u};
    uint4 afc = z4, afn = z4;              // A ring; lanes lr!=0 stay zero

    for (int t = 0; t < T; t++) {
        const unsigned short* hb = hbuf[t & 1];
        unsigned short* hn = hbuf[(t + 1) & 1];

        // prefetch next step's xz (used at gate time next iteration)
        const XZT* xzt1 = xzb + (size_t)(t + 1 < T ? t + 1 : t) * FU;
        if (q == 0) {
#pragma unroll
            for (int g2 = 0; g2 < 4; g2++) {
                xn[2 * g2]     = ldxz1(xzt1 + g2 * 256 + u0);
                xn[2 * g2 + 1] = ldxz1(xzt1 + g2 * 256 + u0 + 16);
            }
        }

        // ---- half A: unit u0; strips Wr[0](i) Wr[2](f) Wr[4](g) + Wl[2w](o)
        {
            floatx4 acc_i = {0.f,0.f,0.f,0.f}, acc_f = {0.f,0.f,0.f,0.f};
            floatx4 acc_g = {0.f,0.f,0.f,0.f}, acc_o = {0.f,0.f,0.f,0.f};
            if (lr == 0) afc = *(const uint4*)(hb + q * 8);
            uint4 stc = Wl[(2 * w * 8) * 64 + lane], stn = z4;
#pragma unroll
            for (int kc = 0; kc < 8; kc++) {
                if (kc < 7) {
                    if (lr == 0) afn = *(const uint4*)(hb + (kc + 1) * 32 + q * 8);
                    stn = Wl[(2 * w * 8 + kc + 1) * 64 + lane];
                }
                acc_i = __builtin_amdgcn_mfma_f32_16x16x32_f16(h8c(afc), h8c(Wr[0][kc]), acc_i, 0, 0, 0);
                acc_f = __builtin_amdgcn_mfma_f32_16x16x32_f16(h8c(afc), h8c(Wr[2][kc]), acc_f, 0, 0, 0);
                acc_g = __builtin_amdgcn_mfma_f32_16x16x32_f16(h8c(afc), h8c(Wr[4][kc]), acc_g, 0, 0, 0);
                acc_o = __builtin_amdgcn_mfma_f32_16x16x32_f16(h8c(afc), h8c(stc),       acc_o, 0, 0, 0);
                afc = afn; stc = stn;
            }
            const float zi = acc_i[0] + xc[0];
            const float zf = acc_f[0] + xc[2];
            const float zg = acc_g[0] + xc[4];
            const float zo = acc_o[0] + xc[6];
            const float iv = sigmf(zi), fv = sigmf(zf);
            const float gv = tanhfast(zg), ov = sigmf(zo);
            c0 = fv * c0 + iv * gv;
            const float hv = ov * tanhfast(c0);
            if (q == 0) {
                hn[u0] = __builtin_bit_cast(unsigned short, (_Float16)hv);
                hsb[(size_t)t * U + u0] = f2bf(hv);
            }
        }

        // ---- half B: unit u0+16; strips Wr[1] Wr[3] Wr[5] + Wl[2w+1]
        {
            floatx4 acc_i = {0.f,0.f,0.f,0.f}, acc_f = {0.f,0.f,0.f,0.f};
            floatx4 acc_g = {0.f,0.f,0.f,0.f}, acc_o = {0.f,0.f,0.f,0.f};
            if (lr == 0) afc = *(const uint4*)(hb + q * 8);
            uint4 stc = Wl[((2 * w + 1) * 8) * 64 + lane], stn = z4;
#pragma unroll
            for (int kc = 0; kc < 8; kc++) {
                if (kc < 7) {
                    if (lr == 0) afn = *(const uint4*)(hb + (kc + 1) * 32 + q * 8);
                    stn = Wl[((2 * w + 1) * 8 + kc + 1) * 64 + lane];
                }
                acc_i = __builtin_amdgcn_mfma_f32_16x16x32_f16(h8c(afc), h8c(Wr[1][kc]), acc_i, 0, 0, 0);
                acc_f = __builtin_amdgcn_mfma_f32_16x16x32_f16(h8c(afc), h8c(Wr[3][kc]), acc_f, 0, 0, 0);
                acc_g = __builtin_amdgcn_mfma_f32_16x16x32_f16(h8c(afc), h8c(Wr[5][kc]), acc_g, 0, 0, 0);
                acc_o = __builtin_amdgcn_mfma_f32_16x16x32_f16(h8c(afc), h8c(stc),       acc_o, 0, 0, 0);
                afc = afn; stc = stn;
            }
            const float zi = acc_i[0] + xc[1];
            const float zf = acc_f[0] + xc[3];
            const float zg = acc_g[0] + xc[5];
            const float zo = acc_o[0] + xc[7];
            const float iv = sigmf(zi), fv = sigmf(zf);
            const float gv = tanhfast(zg), ov = sigmf(zo);
            c1 = fv * c1 + iv * gv;
            const float hv = ov * tanhfast(c1);
            if (q == 0) {
                hn[u0 + 16] = __builtin_bit_cast(unsigned short, (_Float16)hv);
                hsb[(size_t)t * U + u0 + 16] = f2bf(hv);
            }
        }

#pragma unroll
        for (int i = 0; i < 8; i++) xc[i] = xn[i];
        __syncthreads();
    }
}

// ---------------------------------------------------------------------------
extern "C" void kernel_launch(void* const* d_in, const int* in_sizes, int n_in,
                              void* d_out, int out_size, void* d_ws, size_t ws_size,
                              hipStream_t stream)
{
    const float* x    = (const float*)d_in[0];
    const float* w_in = (const float*)d_in[1];
    const float* b_in = (const float*)d_in[2];
    const float* kern = (const float*)d_in[3];
    const float* rec  = (const float*)d_in[4];
    const float* bias = (const float*)d_in[5];
    const float* wout = (const float*)d_in[6];
    const float* bout = (const float*)d_in[7];

    char* ws = (char*)d_ws;
    const size_t rec_bytes = (size_t)64 * 8 * 64 * 16;    // 512 KiB packed W frags
    const size_t xin_bytes = (size_t)M * D * 2;           // 16 MiB
    const size_t hs_bytes  = (size_t)M * U * 2;           // 16 MiB
    const size_t xz32_bytes = (size_t)M * FU * 4;         // 128 MiB
    const size_t base = rec_bytes + xin_bytes + hs_bytes;

    uint4* P = (uint4*)ws;
    unsigned short* xin_bf = (unsigned short*)(ws + rec_bytes);
    unsigned short* hs_bf  = (unsigned short*)(ws + rec_bytes + xin_bytes);
    char* xz_raw = ws + base;

    const bool use_f32 = ws_size >= base + xz32_bytes;

    // pack rec_kernel -> f16 MFMA fragment layout (every launch; ws re-poisoned)
    pack_rec_mfma<<<128, 256, 0, stream>>>(rec, P);

    // GEMM1: xin = bf16(x @ w_in + b_in)   [M,512]x[512,256]
    gemm_mfma<512, 256, 16, 2, false><<<(256 / 32) * (M / 256), 64, 0, stream>>>(
        x, w_in, b_in, (void*)xin_bf);

    if (use_f32) {
        float* xz = (float*)xz_raw;
        // GEMM2: xz = fp32(xin @ kernel + bias)  [M,256]x[256,1024]
        gemm_mfma<256, 1024, 16, 2, true><<<(1024 / 32) * (M / 256), 64, 0, stream>>>(
            xin_bf, kern, bias, (void*)xz);
        lstm_mfma<float><<<Bsz, 512, 0, stream>>>(xz, P, hs_bf);
    } else {
        unsigned short* xz = (unsigned short*)xz_raw;
        gemm_mfma<256, 1024, 16, 2, false><<<(1024 / 32) * (M / 256), 64, 0, stream>>>(
            xin_bf, kern, bias, (void*)xz);
        lstm_mfma<unsigned short><<<Bsz, 512, 0, stream>>>(xz, P, hs_bf);
    }

    // GEMM3: out = fp32(hs @ w_out + b_out)  [M,256]x[256,256]
    gemm_mfma<256, 256, 16, 2, true><<<(256 / 32) * (M / 256), 64, 0, stream>>>(
        hs_bf, wout, bout, d_out);
}